// Round 6
// baseline (274.691 us; speedup 1.0000x reference)
//
#include <hip/hip_runtime.h>
#include <math.h>

// Problem constants (from reference)
#define BATCH 262144
#define DIM   128
#define NCLS  40
#define NCP   48             // classes padded to 3 MFMA tiles of 16
#define CD    (NCLS * DIM)   // 5120
// LAMBDA_R=1.0, LAMBDA_C=0.5, LAMBDA_M=1.0, MOMENTUM=0.1

#define TB1 512            // k1: 8 waves/block
#define NB1 256            // k1 blocks: 1024 rows/block (5.24 MB partials)
#define TB3 256            // k3: 4 waves/block, 64 rows/wave
#define NB3 (BATCH / 256)  // 1024 blocks

typedef __attribute__((ext_vector_type(8))) short short8;  // 8 bf16 = 4 VGPRs
typedef __attribute__((ext_vector_type(4))) float f32x4;   // MFMA C/D

// fp32 -> bf16 round-to-nearest-even (bit trick; inputs are finite)
__device__ __forceinline__ short f2bf(float f) {
    unsigned u = __float_as_uint(f);
    u += 0x7fffu + ((u >> 16) & 1u);
    return (short)(u >> 16);
}

// 40 named float2 accumulators. Round-5 post-mortem: a bare switch gets
// IF-CONVERTED into ~80 predicated VALU ops per row (VALUBusy showed ~68
// instrs/iter). The volatile asm register-tie in each case body makes the
// case non-speculatable -> compiler must emit a real (wave-uniform, scalar)
// branch: ~15 cyc/row instead of ~160.
#define K1_ALL(M) M(0) M(1) M(2) M(3) M(4) M(5) M(6) M(7) M(8) M(9) \
                  M(10) M(11) M(12) M(13) M(14) M(15) M(16) M(17) M(18) M(19) \
                  M(20) M(21) M(22) M(23) M(24) M(25) M(26) M(27) M(28) M(29) \
                  M(30) M(31) M(32) M(33) M(34) M(35) M(36) M(37) M(38) M(39)
#define K1_DECL(c) float2 a##c = {0.0f, 0.0f};
#define K1_CASE(c) case c: a##c.x += vv.x; a##c.y += vv.y; \
    asm volatile("" : "+v"(a##c.x), "+v"(a##c.y)); break;
#define K1_ACCUM(CLS, V) { const float2 vv = (V); \
    switch (CLS) { K1_ALL(K1_CASE) default: break; } }
#define K1_STA(c)  s_bufA[(c) * 64 + lane] = a##c;
#define K1_STB(c)  s_bufB[(c) * 64 + lane] = a##c;
#define K1_RMWA(c) { float2 t_ = s_bufA[(c) * 64 + lane]; \
                     t_.x += a##c.x; t_.y += a##c.y; \
                     s_bufA[(c) * 64 + lane] = t_; }
#define K1_RMWB(c) { float2 t_ = s_bufB[(c) * 64 + lane]; \
                     t_.x += a##c.x; t_.y += a##c.y; \
                     s_bufB[(c) * 64 + lane] = t_; }

__device__ __forceinline__ void k1_stage(const float* src, float* dst) {
    // 64 lanes x 16 B = 1024 B (2 rows). Global src per-lane; LDS dst
    // wave-uniform base + lane*16 (HW rule). Fire-and-forget, vmcnt-counted.
    __builtin_amdgcn_global_load_lds(
        (const __attribute__((address_space(1))) void*)src,
        (__attribute__((address_space(3))) void*)dst, 16, 0, 0);
}

// ---------------------------------------------------------------------------
// K1: segmented sum via global_load_lds ring.
// Each wave owns 128 rows, streamed through a wave-PRIVATE 8-slot LDS ring
// (slot = 2 rows = 1 KB). Explicit counted s_waitcnt vmcnt(7) (T4 idiom)
// guarantees the consumed slot's DMA completed; latency hiding comes from
// the 8-deep DMA queue (8 KB in flight/wave, 64 KB/CU), NOT from compiler
// VGPR-ring scheduling (which rounds 0/4/5 proved never works: ~900cyc/iter).
// Accumulate: lane owns dims {2l,2l+1}; 40 VGPR float2 accs, forced-branch
// switch on the wave-uniform class (readlane). No barriers in the hot loop.
// Combine: 2 parallel LDS buffers, 4 phases. Even worst-case (compiler adds
// conservative drains) the 8 waves self-overlap to ~26us.
// ---------------------------------------------------------------------------
__global__ __launch_bounds__(TB1) void k1_segsum(const float* __restrict__ z,
                                                 const int* __restrict__ y,
                                                 float* __restrict__ ps,
                                                 float* __restrict__ gcnt) {
    __shared__ float  s_ring[8][8 * 256];   // 65536 B: 8 waves x 8 slots x 1KB
    __shared__ float2 s_bufA[NCLS * 64];    // 20480 B
    __shared__ float2 s_bufB[NCLS * 64];    // 20480 B
    __shared__ float  s_cnt[NCLS];

    const int t    = threadIdx.x;
    const int w    = t >> 6;
    const int lane = t & 63;
    if (t < NCLS) s_cnt[t] = 0.0f;
    __syncthreads();

    const int rbase = blockIdx.x * 1024 + w * 128;   // wave's 128 rows

    // lane holds y[2*lane], y[2*lane+1] of the wave's rows
    const int2 y2 = *(const int2*)(y + rbase + lane * 2);
    atomicAdd(&s_cnt[y2.x], 1.0f);
    atomicAdd(&s_cnt[y2.y], 1.0f);

    const float* __restrict__ zw = z + (size_t)rbase * DIM;
    float* __restrict__ ringw = s_ring[w];

    // prologue: stage pairs 0..7
#pragma unroll
    for (int p = 0; p < 8; ++p)
        k1_stage(zw + (size_t)p * 256 + lane * 4, ringw + p * 256);

    K1_ALL(K1_DECL)

#pragma unroll 1
    for (int p = 0; p < 56; ++p) {
        asm volatile("s_waitcnt vmcnt(7)" ::: "memory");
        __builtin_amdgcn_sched_barrier(0);
        const int slot = p & 7;
        const float2 v0 = *(const float2*)(ringw + slot * 256 + lane * 2);
        const float2 v1 = *(const float2*)(ringw + slot * 256 + 128 + lane * 2);
        const int c0 = __builtin_amdgcn_readlane(y2.x, p);
        const int c1 = __builtin_amdgcn_readlane(y2.y, p);
        K1_ACCUM(c0, v0)
        K1_ACCUM(c1, v1)
        // refill this slot with pair p+8 (lands ~900cyc later; reads above
        // complete in ~64cyc -- no WAR hazard)
        k1_stage(zw + (size_t)(p + 8) * 256 + lane * 4, ringw + slot * 256);
    }

    // tail pairs 56..63: counted waits 7..0, no refill
#define K1_TAIL(P, W) { \
        asm volatile("s_waitcnt vmcnt(" #W ")" ::: "memory"); \
        __builtin_amdgcn_sched_barrier(0); \
        const int slot = (P) & 7; \
        const float2 v0 = *(const float2*)(ringw + slot * 256 + lane * 2); \
        const float2 v1 = *(const float2*)(ringw + slot * 256 + 128 + lane * 2); \
        const int c0 = __builtin_amdgcn_readlane(y2.x, (P)); \
        const int c1 = __builtin_amdgcn_readlane(y2.y, (P)); \
        K1_ACCUM(c0, v0) \
        K1_ACCUM(c1, v1) }
    K1_TAIL(56, 7) K1_TAIL(57, 6) K1_TAIL(58, 5) K1_TAIL(59, 4)
    K1_TAIL(60, 3) K1_TAIL(61, 2) K1_TAIL(62, 1) K1_TAIL(63, 0)
#undef K1_TAIL

    // ---- combine 8 waves via 2 parallel buffers, 4 phases ----
    __syncthreads();
    if (w == 0) { K1_ALL(K1_STA) }
    if (w == 1) { K1_ALL(K1_STB) }
    __syncthreads();
    if (w == 2) { K1_ALL(K1_RMWA) }
    if (w == 3) { K1_ALL(K1_RMWB) }
    __syncthreads();
    if (w == 4) { K1_ALL(K1_RMWA) }
    if (w == 5) { K1_ALL(K1_RMWB) }
    __syncthreads();
    if (w == 6) { K1_ALL(K1_RMWA) }
    if (w == 7) { K1_ALL(K1_RMWB) }
    __syncthreads();

    // write out: float2 index i = (class*64 + lane) covers dims {2l,2l+1}
    float2* __restrict__ psb = (float2*)(ps + (size_t)blockIdx.x * CD);
    for (int i = t; i < NCLS * 64; i += TB1) {
        const float2 A = s_bufA[i], B = s_bufB[i];
        psb[i] = make_float2(A.x + B.x, A.y + B.y);
    }
    if (t < NCLS) atomicAdd(&gcnt[t], s_cnt[t]);
}

// ---------------------------------------------------------------------------
// K2: reduce partials -> EMA centers; emit bf16 c [48][128] + fp32 c2 halves.
// Re-gridded: 96 blocks = (class 0..47) x (dim-half), 512 threads =
// 64 dims x 8 slices -> each thread sums only 32 strided values (8-way ILP
// via unroll) instead of 64 serial. c2 emitted per half; k3 sums the halves.
// ---------------------------------------------------------------------------
__global__ __launch_bounds__(512) void k2_centers(const float* __restrict__ ps,
                                                  const float* __restrict__ gcnt,
                                                  const float* __restrict__ centers,
                                                  short* __restrict__ cbf,
                                                  float* __restrict__ c2p) {
    const int j    = blockIdx.x >> 1;   // class 0..47
    const int half = blockIdx.x & 1;
    const int t    = threadIdx.x;
    const int dl   = t & 63;
    const int d    = half * 64 + dl;
    const int s    = t >> 6;            // slice 0..7

    if (j >= NCLS) {
        if (s == 0) cbf[j * DIM + d] = 0;
        if (t == 0) c2p[blockIdx.x] = 5e29f;   // halves sum to 1e30
        return;                          // uniform: whole block exits
    }

    const float* __restrict__ p = ps + j * DIM + d + (size_t)(s * 32) * CD;
    float sum = 0.0f;
#pragma unroll 8
    for (int b = 0; b < 32; ++b) sum += p[(size_t)b * CD];

    __shared__ float red[512];
    red[t] = sum;
    __syncthreads();

    if (s == 0) {   // t == dl < 64
        float tot = 0.0f;
#pragma unroll
        for (int k = 0; k < 8; ++k) tot += red[(k << 6) | dl];
        const float cnt  = gcnt[j];
        const float mean = tot / fmaxf(cnt, 1.0f);
        const float ctr  = centers[j * DIM + d];
        const float ema  = 0.9f * ctr + 0.1f * mean;
        const float cv   = (cnt > 0.0f) ? ema : ctr;
        cbf[j * DIM + d] = f2bf(cv);
        red[t] = cv * cv;
    }
    __syncthreads();
    if (t == 0) {
        float sc = 0.0f;
#pragma unroll 8
        for (int i = 0; i < 64; ++i) sc += red[i];
        c2p[blockIdx.x] = sc;
    }
}

// ---------------------------------------------------------------------------
// K3: MFMA Gram kernel (round-4/5 proven body). Per wave: 64 rows x 48
// classes via 16x16x32 bf16 MFMA. z2 in col 48 of stride-52 s_S rows; s_red
// aliased onto s_S; k4 fused via one atomicAdd (out pre-zeroed).
// Only change: s_c2 = sum of the two per-half c2 partials from k2.
// D layout: col=lane&15 (class), row=(lane>>4)*4+reg  [m89-verified].
// ---------------------------------------------------------------------------
__global__ __launch_bounds__(TB3) void k3_loss(const float* __restrict__ z,
                                               const int* __restrict__ y,
                                               const short* __restrict__ cbf,
                                               const float* __restrict__ c2p,
                                               const float* __restrict__ tr,
                                               const float* __restrict__ mg,
                                               float* __restrict__ out) {
    __shared__ float s_S[4][64 * 52];   // 53248 B; col 48 of each row = z2
    __shared__ float s_c2[NCP];         // 192 B

    const int t = threadIdx.x;
    if (t < NCP) s_c2[t] = c2p[2 * t] + c2p[2 * t + 1];

    const int w    = t >> 6;
    const int lane = t & 63;
    const int q    = lane >> 4;     // k-quad 0..3
    const int col  = lane & 15;
    const int wavebase = blockIdx.x * 256 + w * 64;

    // B fragments, preloaded once: 12 x short8 (48 VGPRs)
    short8 bfrag[3][4];
#pragma unroll
    for (int ct = 0; ct < 3; ++ct)
#pragma unroll
        for (int s = 0; s < 4; ++s)
            bfrag[ct][s] = *(const short8*)(cbf + (ct * 16 + col) * DIM + s * 32 + q * 8);

    __syncthreads();   // s_c2 visible to all waves

#pragma unroll 1
    for (int rt = 0; rt < 4; ++rt) {
        const float* __restrict__ zrow =
            z + (size_t)(wavebase + rt * 16 + col) * DIM + q * 8;

        float4 f[8];
#pragma unroll
        for (int s = 0; s < 4; ++s) {
            f[2 * s]     = *(const float4*)(zrow + s * 32);
            f[2 * s + 1] = *(const float4*)(zrow + s * 32 + 4);
        }

        // exact fp32 partial ||z||^2 over my 32 dims
        float zp = 0.0f;
#pragma unroll
        for (int i = 0; i < 8; ++i) {
            zp = fmaf(f[i].x, f[i].x, zp);
            zp = fmaf(f[i].y, f[i].y, zp);
            zp = fmaf(f[i].z, f[i].z, zp);
            zp = fmaf(f[i].w, f[i].w, zp);
        }

        // convert to bf16 A-fragments
        short8 afr[4];
#pragma unroll
        for (int s = 0; s < 4; ++s) {
            const float4 f0 = f[2 * s], f1 = f[2 * s + 1];
            afr[s][0] = f2bf(f0.x); afr[s][1] = f2bf(f0.y);
            afr[s][2] = f2bf(f0.z); afr[s][3] = f2bf(f0.w);
            afr[s][4] = f2bf(f1.x); afr[s][5] = f2bf(f1.y);
            afr[s][6] = f2bf(f1.z); afr[s][7] = f2bf(f1.w);
        }

        f32x4 acc0 = {0.f, 0.f, 0.f, 0.f};
        f32x4 acc1 = {0.f, 0.f, 0.f, 0.f};
        f32x4 acc2 = {0.f, 0.f, 0.f, 0.f};
#pragma unroll
        for (int s = 0; s < 4; ++s) {
            acc0 = __builtin_amdgcn_mfma_f32_16x16x32_bf16(afr[s], bfrag[0][s], acc0, 0, 0, 0);
            acc1 = __builtin_amdgcn_mfma_f32_16x16x32_bf16(afr[s], bfrag[1][s], acc1, 0, 0, 0);
            acc2 = __builtin_amdgcn_mfma_f32_16x16x32_bf16(afr[s], bfrag[2][s], acc2, 0, 0, 0);
        }

        // z2: reduce the 4 k-quads (lanes xor 16, 32); park in col 48
        zp += __shfl_xor(zp, 16);
        zp += __shfl_xor(zp, 32);
        if (q == 0) s_S[w][(rt * 16 + col) * 52 + 48] = zp;

        // dump S tile: row = rt*16 + q*4 + reg, class = ct*16 + col
#pragma unroll
        for (int reg = 0; reg < 4; ++reg) {
            const int rr = rt * 16 + q * 4 + reg;
            s_S[w][rr * 52 + col]      = acc0[reg];
            s_S[w][rr * 52 + 16 + col] = acc1[reg];
            s_S[w][rr * 52 + 32 + col] = acc2[reg];
        }
    }
    // s_S rows are per-wave private; in-order DS pipe makes them visible
    // to this wave without a barrier.

    // ---- scalar epilogue: 1 thread = 1 row ----
    const int row = blockIdx.x * 256 + t;
    const int cls = y[row];
    const float z2v = s_S[w][lane * 52 + 48];

    float own_d2 = 0.0f;
    float mind2  = 3.4e38f;
#pragma unroll
    for (int k = 0; k < 12; ++k) {
        const float4 Sv = *(const float4*)&s_S[w][lane * 52 + 4 * k];
        const float Se[4] = {Sv.x, Sv.y, Sv.z, Sv.w};
#pragma unroll
        for (int e = 0; e < 4; ++e) {
            const int j = 4 * k + e;
            float d2 = fmaxf(z2v + s_c2[j] - 2.0f * Se[e], 0.0f);
            const bool isown = (j == cls);
            own_d2 = isown ? d2 : own_d2;
            mind2  = isown ? mind2 : fminf(mind2, d2);
        }
    }

    const float r  = sqrtf(z2v);
    const float dd = r - tr[cls];
    const float ad = fabsf(dd);
    const float rad = (ad < 1.0f) ? 0.5f * dd * dd : ad - 0.5f;

    const float dist = sqrtf(mind2);
    const float marg = fmaxf(mg[cls] - dist, 0.0f);

    const float tot = rad + 0.5f * own_d2 + marg;

    // block reduce: alias s_red onto s_S (all s_S reads done after barrier)
    __syncthreads();
    float* s_red = &s_S[0][0];
    s_red[t] = tot;
    __syncthreads();
    for (int off = TB3 / 2; off > 0; off >>= 1) {
        if (t < off) s_red[t] += s_red[t + off];
        __syncthreads();
    }
    if (t == 0) atomicAdd(out, s_red[0] * (1.0f / (float)BATCH));
}

// ---------------------------------------------------------------------------
extern "C" void kernel_launch(void* const* d_in, const int* in_sizes, int n_in,
                              void* d_out, int out_size, void* d_ws, size_t ws_size,
                              hipStream_t stream) {
    const float* z       = (const float*)d_in[0];  // [BATCH, DIM] fp32
    const int*   y       = (const int*)d_in[1];    // [BATCH] int32
    const float* centers = (const float*)d_in[2];  // [NCLS, DIM] fp32
    // d_in[3] = initialized (all True, unused)
    const float* tr      = (const float*)d_in[4];  // [NCLS] target_radii
    const float* mg      = (const float*)d_in[5];  // [NCLS] margins
    float* out = (float*)d_out;

    float* ws        = (float*)d_ws;
    float* part_sums = ws;                                   // NB1*CD (5.24 MB)
    float* c2p       = part_sums + (size_t)NB1 * CD;         // 2*NCP
    float* gcnt      = c2p + 2 * NCP;                        // NCLS
    short* cbf       = (short*)(gcnt + NCLS);                // NCP*DIM bf16

    hipMemsetAsync(gcnt, 0, NCLS * sizeof(float), stream);
    hipMemsetAsync(out, 0, sizeof(float), stream);

    k1_segsum<<<NB1, TB1, 0, stream>>>(z, y, part_sums, gcnt);
    k2_centers<<<2 * NCP, 512, 0, stream>>>(part_sums, gcnt, centers, cbf, c2p);
    k3_loss<<<NB3, TB3, 0, stream>>>(z, y, cbf, c2p, tr, mg, out);
}

// Round 7
// 240.230 us; speedup vs baseline: 1.1434x; 1.1434x over previous
//
#include <hip/hip_runtime.h>
#include <math.h>

// Problem constants (from reference)
#define BATCH 262144
#define DIM   128
#define NCLS  40
#define NCP   48             // classes padded to 3 MFMA tiles of 16
#define CD    (NCLS * DIM)   // 5120
// LAMBDA_R=1.0, LAMBDA_C=0.5, LAMBDA_M=1.0, MOMENTUM=0.1

#define TB1 256            // k1: 4 waves/block
#define NB1 256            // k1 blocks: 1024 rows/block (5.24 MB partials)
#define TB3 256            // k3: 4 waves/block, 64 rows/wave
#define NB3 (BATCH / 256)  // 1024 blocks

typedef __attribute__((ext_vector_type(8))) short short8;  // 8 bf16 = 4 VGPRs
typedef __attribute__((ext_vector_type(4))) float f32x4;   // MFMA C/D

// fp32 -> bf16 round-to-nearest-even (bit trick; inputs are finite)
__device__ __forceinline__ short f2bf(float f) {
    unsigned u = __float_as_uint(f);
    u += 0x7fffu + ((u >> 16) & 1u);
    return (short)(u >> 16);
}

// ---------------------------------------------------------------------------
// K1: segmented sum -- NO per-row class dispatch.
// Rounds 0/2/4/5/6 post-mortem: every 40-way dispatch form (LDS-RMW chain,
// ds_add_f32, if-converted switch ~80 VALU ops/row, forced-branch switch
// ~500 SALU cyc/row) costs 100-500cyc/row. This version computes the scatter
// target as a PER-LANE ADDRESS instead:
//   * wave-instr loads 2 consecutive rows (64 lanes x float4 = 1KB,
//     perfectly coalesced -- also kills the 64-transactions/instr cost of
//     the old strided layouts);
//   * lanes 0-31 carry row r (class c0), lanes 32-63 row r+1 (c1);
//   * each lane RMWs its wave-private LDS acc at cls_sel*512B+(lane&31)*16B,
//     cls_sel = one v_cndmask. Per 2 rows: ds_read_b128 + 4 add +
//     ds_write_b128 + ~6 ops (~80cyc vs 300-1000 before).
//   * c0==c1 (p~3.3%): both halves would RMW the SAME addresses -> combine
//     halves via shfl_xor(32) first, then half-wave RMW (wave-uniform branch).
// 4 waves x 20KB private acc = 80KB LDS; combine 4->1 at the end.
// ---------------------------------------------------------------------------
__global__ __launch_bounds__(TB1) void k1_segsum(const float* __restrict__ z,
                                                 const int* __restrict__ y,
                                                 float* __restrict__ ps,
                                                 float* __restrict__ gcnt) {
    __shared__ float s_acc[4][NCLS * DIM];   // 81920 B, per-wave private
    __shared__ float s_cnt[NCLS];

    const int t    = threadIdx.x;
    const int w    = t >> 6;
    const int lane = t & 63;

    {   // zero accumulators (vectorized)
        float4* az = (float4*)&s_acc[0][0];
        const float4 z4 = make_float4(0.f, 0.f, 0.f, 0.f);
        for (int i = t; i < 4 * NCLS * DIM / 4; i += TB1) az[i] = z4;
        if (t < NCLS) s_cnt[t] = 0.0f;
    }
    __syncthreads();

    const int rbase = blockIdx.x * 1024 + w * 256;   // wave's 256 rows

    // lane holds class-pairs: yA = rows (2l, 2l+1), yB = rows (128+2l, 129+2l)
    const int2 yA = ((const int2*)(y + rbase))[lane];
    const int2 yB = ((const int2*)(y + rbase + 128))[lane];
    atomicAdd(&s_cnt[yA.x], 1.0f);
    atomicAdd(&s_cnt[yA.y], 1.0f);
    atomicAdd(&s_cnt[yB.x], 1.0f);
    atomicAdd(&s_cnt[yB.y], 1.0f);

    const float* __restrict__ zw = z + (size_t)rbase * DIM;
    float* __restrict__ accw = s_acc[w];

    // 8-deep coalesced prefetch ring: group g = rows (2g, 2g+1) = 1KB
    float4 vb[8];
#pragma unroll
    for (int q = 0; q < 8; ++q)
        vb[q] = *(const float4*)(zw + (size_t)q * 256 + lane * 4);

    // one macro per 64-group half so all ring indices stay compile-time
#define K1_HALF(YH, GB, CLAMP)                                                \
    _Pragma("unroll 1")                                                       \
    for (int i0 = 0; i0 < 64; i0 += 8) {                                      \
        _Pragma("unroll")                                                     \
        for (int q = 0; q < 8; ++q) {                                         \
            const int i2 = i0 + q;                                            \
            float4 v = vb[q];                                                 \
            int g = (GB) + i2 + 8;                                            \
            if (CLAMP && g > 127) g = (GB) + i2;  /* harmless self-reload */  \
            vb[q] = *(const float4*)(zw + (size_t)g * 256 + lane * 4);        \
            const int c0 = __builtin_amdgcn_readlane((YH).x, i2);             \
            const int c1 = __builtin_amdgcn_readlane((YH).y, i2);             \
            if (c0 != c1) {  /* wave-uniform; halves hit disjoint rows */     \
                const int cls = (lane < 32) ? c0 : c1;                        \
                float4* ap = (float4*)&accw[cls * DIM] + (lane & 31);         \
                float4 o = *ap;                                               \
                o.x += v.x; o.y += v.y; o.z += v.z; o.w += v.w;               \
                *ap = o;                                                      \
            } else {         /* same class: combine halves, half-wave RMW */  \
                v.x += __shfl_xor(v.x, 32);                                   \
                v.y += __shfl_xor(v.y, 32);                                   \
                v.z += __shfl_xor(v.z, 32);                                   \
                v.w += __shfl_xor(v.w, 32);                                   \
                if (lane < 32) {                                              \
                    float4* ap = (float4*)&accw[c0 * DIM] + lane;             \
                    float4 o = *ap;                                           \
                    o.x += v.x; o.y += v.y; o.z += v.z; o.w += v.w;           \
                    *ap = o;                                                  \
                }                                                             \
            }                                                                 \
        }                                                                     \
    }

    K1_HALF(yA, 0, 0)     // groups 0..63, reloads reach 71 (< 128, no clamp)
    K1_HALF(yB, 64, 1)    // groups 64..127, clamp tail reloads
#undef K1_HALF

    __syncthreads();

    // combine 4 waves -> block partial (coalesced float4 store)
    float4* __restrict__ psb = (float4*)(ps + (size_t)blockIdx.x * CD);
    const float4* a0 = (const float4*)s_acc[0];
    const float4* a1 = (const float4*)s_acc[1];
    const float4* a2 = (const float4*)s_acc[2];
    const float4* a3 = (const float4*)s_acc[3];
#pragma unroll
    for (int k = 0; k < 5; ++k) {
        const int j = t + k * TB1;          // j < 1280 = CD/4
        const float4 p0 = a0[j], p1 = a1[j], p2 = a2[j], p3 = a3[j];
        float4 r;
        r.x = (p0.x + p1.x) + (p2.x + p3.x);
        r.y = (p0.y + p1.y) + (p2.y + p3.y);
        r.z = (p0.z + p1.z) + (p2.z + p3.z);
        r.w = (p0.w + p1.w) + (p2.w + p3.w);
        psb[j] = r;
    }
    if (t < NCLS) atomicAdd(&gcnt[t], s_cnt[t]);
}

// ---------------------------------------------------------------------------
// K2: reduce partials -> EMA centers; emit bf16 c [48][128] + fp32 c2 halves.
// (round-6 proven, unchanged) 96 blocks = class x dim-half, 8-way slice ILP.
// ---------------------------------------------------------------------------
__global__ __launch_bounds__(512) void k2_centers(const float* __restrict__ ps,
                                                  const float* __restrict__ gcnt,
                                                  const float* __restrict__ centers,
                                                  short* __restrict__ cbf,
                                                  float* __restrict__ c2p) {
    const int j    = blockIdx.x >> 1;   // class 0..47
    const int half = blockIdx.x & 1;
    const int t    = threadIdx.x;
    const int dl   = t & 63;
    const int d    = half * 64 + dl;
    const int s    = t >> 6;            // slice 0..7

    if (j >= NCLS) {
        if (s == 0) cbf[j * DIM + d] = 0;
        if (t == 0) c2p[blockIdx.x] = 5e29f;   // halves sum to 1e30
        return;                          // uniform: whole block exits
    }

    const float* __restrict__ p = ps + j * DIM + d + (size_t)(s * 32) * CD;
    float sum = 0.0f;
#pragma unroll 8
    for (int b = 0; b < 32; ++b) sum += p[(size_t)b * CD];

    __shared__ float red[512];
    red[t] = sum;
    __syncthreads();

    if (s == 0) {   // t == dl < 64
        float tot = 0.0f;
#pragma unroll
        for (int k = 0; k < 8; ++k) tot += red[(k << 6) | dl];
        const float cnt  = gcnt[j];
        const float mean = tot / fmaxf(cnt, 1.0f);
        const float ctr  = centers[j * DIM + d];
        const float ema  = 0.9f * ctr + 0.1f * mean;
        const float cv   = (cnt > 0.0f) ? ema : ctr;
        cbf[j * DIM + d] = f2bf(cv);
        red[t] = cv * cv;
    }
    __syncthreads();
    if (t == 0) {
        float sc = 0.0f;
#pragma unroll 8
        for (int i = 0; i < 64; ++i) sc += red[i];
        c2p[blockIdx.x] = sc;
    }
}

// ---------------------------------------------------------------------------
// K3: MFMA Gram kernel (round-4/5/6 proven body, unchanged). Per wave: 64
// rows x 48 classes via 16x16x32 bf16 MFMA. z2 in col 48 of stride-52 s_S
// rows; s_red aliased onto s_S; k4 fused via one atomicAdd (out pre-zeroed).
// s_c2 = sum of the two per-half c2 partials from k2.
// D layout: col=lane&15 (class), row=(lane>>4)*4+reg  [m89-verified].
// ---------------------------------------------------------------------------
__global__ __launch_bounds__(TB3) void k3_loss(const float* __restrict__ z,
                                               const int* __restrict__ y,
                                               const short* __restrict__ cbf,
                                               const float* __restrict__ c2p,
                                               const float* __restrict__ tr,
                                               const float* __restrict__ mg,
                                               float* __restrict__ out) {
    __shared__ float s_S[4][64 * 52];   // 53248 B; col 48 of each row = z2
    __shared__ float s_c2[NCP];         // 192 B

    const int t = threadIdx.x;
    if (t < NCP) s_c2[t] = c2p[2 * t] + c2p[2 * t + 1];

    const int w    = t >> 6;
    const int lane = t & 63;
    const int q    = lane >> 4;     // k-quad 0..3
    const int col  = lane & 15;
    const int wavebase = blockIdx.x * 256 + w * 64;

    // B fragments, preloaded once: 12 x short8 (48 VGPRs)
    short8 bfrag[3][4];
#pragma unroll
    for (int ct = 0; ct < 3; ++ct)
#pragma unroll
        for (int s = 0; s < 4; ++s)
            bfrag[ct][s] = *(const short8*)(cbf + (ct * 16 + col) * DIM + s * 32 + q * 8);

    __syncthreads();   // s_c2 visible to all waves

#pragma unroll 1
    for (int rt = 0; rt < 4; ++rt) {
        const float* __restrict__ zrow =
            z + (size_t)(wavebase + rt * 16 + col) * DIM + q * 8;

        float4 f[8];
#pragma unroll
        for (int s = 0; s < 4; ++s) {
            f[2 * s]     = *(const float4*)(zrow + s * 32);
            f[2 * s + 1] = *(const float4*)(zrow + s * 32 + 4);
        }

        // exact fp32 partial ||z||^2 over my 32 dims
        float zp = 0.0f;
#pragma unroll
        for (int i = 0; i < 8; ++i) {
            zp = fmaf(f[i].x, f[i].x, zp);
            zp = fmaf(f[i].y, f[i].y, zp);
            zp = fmaf(f[i].z, f[i].z, zp);
            zp = fmaf(f[i].w, f[i].w, zp);
        }

        // convert to bf16 A-fragments
        short8 afr[4];
#pragma unroll
        for (int s = 0; s < 4; ++s) {
            const float4 f0 = f[2 * s], f1 = f[2 * s + 1];
            afr[s][0] = f2bf(f0.x); afr[s][1] = f2bf(f0.y);
            afr[s][2] = f2bf(f0.z); afr[s][3] = f2bf(f0.w);
            afr[s][4] = f2bf(f1.x); afr[s][5] = f2bf(f1.y);
            afr[s][6] = f2bf(f1.z); afr[s][7] = f2bf(f1.w);
        }

        f32x4 acc0 = {0.f, 0.f, 0.f, 0.f};
        f32x4 acc1 = {0.f, 0.f, 0.f, 0.f};
        f32x4 acc2 = {0.f, 0.f, 0.f, 0.f};
#pragma unroll
        for (int s = 0; s < 4; ++s) {
            acc0 = __builtin_amdgcn_mfma_f32_16x16x32_bf16(afr[s], bfrag[0][s], acc0, 0, 0, 0);
            acc1 = __builtin_amdgcn_mfma_f32_16x16x32_bf16(afr[s], bfrag[1][s], acc1, 0, 0, 0);
            acc2 = __builtin_amdgcn_mfma_f32_16x16x32_bf16(afr[s], bfrag[2][s], acc2, 0, 0, 0);
        }

        // z2: reduce the 4 k-quads (lanes xor 16, 32); park in col 48
        zp += __shfl_xor(zp, 16);
        zp += __shfl_xor(zp, 32);
        if (q == 0) s_S[w][(rt * 16 + col) * 52 + 48] = zp;

        // dump S tile: row = rt*16 + q*4 + reg, class = ct*16 + col
#pragma unroll
        for (int reg = 0; reg < 4; ++reg) {
            const int rr = rt * 16 + q * 4 + reg;
            s_S[w][rr * 52 + col]      = acc0[reg];
            s_S[w][rr * 52 + 16 + col] = acc1[reg];
            s_S[w][rr * 52 + 32 + col] = acc2[reg];
        }
    }
    // s_S rows are per-wave private; in-order DS pipe makes them visible
    // to this wave without a barrier.

    // ---- scalar epilogue: 1 thread = 1 row ----
    const int row = blockIdx.x * 256 + t;
    const int cls = y[row];
    const float z2v = s_S[w][lane * 52 + 48];

    float own_d2 = 0.0f;
    float mind2  = 3.4e38f;
#pragma unroll
    for (int k = 0; k < 12; ++k) {
        const float4 Sv = *(const float4*)&s_S[w][lane * 52 + 4 * k];
        const float Se[4] = {Sv.x, Sv.y, Sv.z, Sv.w};
#pragma unroll
        for (int e = 0; e < 4; ++e) {
            const int j = 4 * k + e;
            float d2 = fmaxf(z2v + s_c2[j] - 2.0f * Se[e], 0.0f);
            const bool isown = (j == cls);
            own_d2 = isown ? d2 : own_d2;
            mind2  = isown ? mind2 : fminf(mind2, d2);
        }
    }

    const float r  = sqrtf(z2v);
    const float dd = r - tr[cls];
    const float ad = fabsf(dd);
    const float rad = (ad < 1.0f) ? 0.5f * dd * dd : ad - 0.5f;

    const float dist = sqrtf(mind2);
    const float marg = fmaxf(mg[cls] - dist, 0.0f);

    const float tot = rad + 0.5f * own_d2 + marg;

    // block reduce: alias s_red onto s_S (all s_S reads done after barrier)
    __syncthreads();
    float* s_red = &s_S[0][0];
    s_red[t] = tot;
    __syncthreads();
    for (int off = TB3 / 2; off > 0; off >>= 1) {
        if (t < off) s_red[t] += s_red[t + off];
        __syncthreads();
    }
    if (t == 0) atomicAdd(out, s_red[0] * (1.0f / (float)BATCH));
}

// ---------------------------------------------------------------------------
extern "C" void kernel_launch(void* const* d_in, const int* in_sizes, int n_in,
                              void* d_out, int out_size, void* d_ws, size_t ws_size,
                              hipStream_t stream) {
    const float* z       = (const float*)d_in[0];  // [BATCH, DIM] fp32
    const int*   y       = (const int*)d_in[1];    // [BATCH] int32
    const float* centers = (const float*)d_in[2];  // [NCLS, DIM] fp32
    // d_in[3] = initialized (all True, unused)
    const float* tr      = (const float*)d_in[4];  // [NCLS] target_radii
    const float* mg      = (const float*)d_in[5];  // [NCLS] margins
    float* out = (float*)d_out;

    float* ws        = (float*)d_ws;
    float* part_sums = ws;                                   // NB1*CD (5.24 MB)
    float* c2p       = part_sums + (size_t)NB1 * CD;         // 2*NCP
    float* gcnt      = c2p + 2 * NCP;                        // NCLS
    short* cbf       = (short*)(gcnt + NCLS);                // NCP*DIM bf16

    hipMemsetAsync(gcnt, 0, NCLS * sizeof(float), stream);
    hipMemsetAsync(out, 0, sizeof(float), stream);

    k1_segsum<<<NB1, TB1, 0, stream>>>(z, y, part_sums, gcnt);
    k2_centers<<<2 * NCP, 512, 0, stream>>>(part_sums, gcnt, centers, cbf, c2p);
    k3_loss<<<NB3, TB3, 0, stream>>>(z, y, cbf, c2p, tr, mg, out);
}